// Round 1
// baseline (497.909 us; speedup 1.0000x reference)
//
#include <hip/hip_runtime.h>

// GraphSAGE 2-layer, N=50000, d=128->32->32, E=800000, fp32.
//
// R6: aggregation is order-free -> delete the fine sort (k_bsort) and CSR
// entirely. k_bscatter's coarse-bucket-grouped ebuf is enough: one block per
// 256-node bucket accumulates neighbor features straight into LDS
// acc[256][32] with ds_add_f32 (lane j -> bank j, conflict-free), counts
// degree with one LDS int atomic per edge, then does the mean/bias/self/relu
// epilogue in-block. Layer-2 projection (h[32] @ [W2l|W2r], 102 MFLOP) is
// fused into that epilogue via a 32-lane __shfl mini-GEMM with W2 staged in
// LDS -> writes zc2[N][64] directly. Layer-2 aggregation = same bucket
// kernel, epilogue writes out.
// Deleted: k_bsort, k_agg x2, kproj L2, adj[], row_ptr[], h round trip.
// ws: zc[N*64] | zc2[N*64] | ebuf[E] | bb[NB+1] | blkhist[GB*NB]  (~29MB)

#define N_NODES 50000
#define NB 196   // coarse buckets = ceil(N/256)
#define GB 256   // blocks in the bucket-count/scatter phases

// ---- unified projection: z[n][0:32)=in@Wl, z[n][32:64)=in@Wr -------------
__global__ __launch_bounds__(256) void kproj(
    const float* __restrict__ in, const float* __restrict__ Wl,
    const float* __restrict__ Wr, float* __restrict__ z, int N, int K) {
  __shared__ float xs[64 * 68];
  __shared__ float ws[64 * 64];
  const int t = threadIdx.x;
  const int n0 = blockIdx.x * 64;
  const int nvalid = (N - n0) < 64 ? (N - n0) : 64;

  const int tx = t & 15, ty = t >> 4;
  const int c0 = tx * 4;
  const int nl = ty * 4;

  float acc[4][4];
#pragma unroll
  for (int i = 0; i < 4; i++)
#pragma unroll
    for (int j = 0; j < 4; j++) acc[i][j] = 0.f;

  for (int kc = 0; kc < K; kc += 64) {
    const int KC = (K - kc) < 64 ? (K - kc) : 64;
    for (int i = t; i < KC * 32; i += 256) {
      int k = i >> 5, c = i & 31;
      ws[k * 64 + c] = Wl[(size_t)(kc + k) * 32 + c];
      ws[k * 64 + 32 + c] = Wr[(size_t)(kc + k) * 32 + c];
    }
    {
      const int kq = KC >> 2;
      const int sh = (KC == 64) ? 4 : 3;
      const int lim = nvalid * kq;
      for (int i = t; i < lim; i += 256) {
        int n = i >> sh, q = i & (kq - 1);
        float4 v = *(const float4*)(in + (size_t)(n0 + n) * K + kc + q * 4);
        *(float4*)(xs + n * 68 + q * 4) = v;
      }
    }
    __syncthreads();

    const float* x0 = xs + (nl + 0) * 68;
    const float* x1 = xs + (nl + 1) * 68;
    const float* x2 = xs + (nl + 2) * 68;
    const float* x3 = xs + (nl + 3) * 68;
    for (int k = 0; k < KC; k += 4) {
      float4 xa = *(const float4*)(x0 + k);
      float4 xb = *(const float4*)(x1 + k);
      float4 xc = *(const float4*)(x2 + k);
      float4 xd = *(const float4*)(x3 + k);
#pragma unroll
      for (int kk = 0; kk < 4; kk++) {
        float4 w = *(const float4*)(ws + (k + kk) * 64 + c0);
        float va = ((const float*)&xa)[kk];
        float vb = ((const float*)&xb)[kk];
        float vc = ((const float*)&xc)[kk];
        float vd = ((const float*)&xd)[kk];
        acc[0][0] += va * w.x; acc[0][1] += va * w.y;
        acc[0][2] += va * w.z; acc[0][3] += va * w.w;
        acc[1][0] += vb * w.x; acc[1][1] += vb * w.y;
        acc[1][2] += vb * w.z; acc[1][3] += vb * w.w;
        acc[2][0] += vc * w.x; acc[2][1] += vc * w.y;
        acc[2][2] += vc * w.z; acc[2][3] += vc * w.w;
        acc[3][0] += vd * w.x; acc[3][1] += vd * w.y;
        acc[3][2] += vd * w.z; acc[3][3] += vd * w.w;
      }
    }
    __syncthreads();
  }
#pragma unroll
  for (int i = 0; i < 4; i++) {
    int node = n0 + nl + i;
    if (node < N) {
      float4 v = make_float4(acc[i][0], acc[i][1], acc[i][2], acc[i][3]);
      *(float4*)(z + (size_t)node * 64 + c0) = v;
    }
  }
}

// ---- phase A: per-block LDS histogram of coarse buckets ------------------
__global__ __launch_bounds__(256) void k_bcount(const int* __restrict__ dst,
                                                int* __restrict__ blkhist,
                                                int E, int chunk) {
  __shared__ int h[NB];
  const int t = threadIdx.x, b = blockIdx.x;
  if (t < NB) h[t] = 0;
  __syncthreads();
  const int e0 = b * chunk;
  int e1 = e0 + chunk;
  if (e1 > E) e1 = E;
  for (int e = e0 + t; e < e1; e += 256) atomicAdd(&h[dst[e] >> 8], 1);
  __syncthreads();
  if (t < NB) blkhist[b * NB + t] = h[t];
}

// ---- phase B: column running sums (in-place) + bucket bases --------------
__global__ __launch_bounds__(256) void k_bscan(int* __restrict__ blkhist,
                                               int* __restrict__ bb, int E) {
  __shared__ int sc[256];
  const int t = threadIdx.x;
  int run = 0;
  if (t < NB) {
    for (int b = 0; b < GB; b += 8) {
      int v[8];
#pragma unroll
      for (int i = 0; i < 8; i++) v[i] = blkhist[(b + i) * NB + t];
#pragma unroll
      for (int i = 0; i < 8; i++) {
        blkhist[(b + i) * NB + t] = run;
        run += v[i];
      }
    }
  }
  sc[t] = (t < NB) ? run : 0;
  __syncthreads();
  for (int off = 1; off < 256; off <<= 1) {
    int tmp = (t >= off) ? sc[t - off] : 0;
    __syncthreads();
    sc[t] += tmp;
    __syncthreads();
  }
  if (t < NB) bb[t] = sc[t] - run;  // exclusive
  if (t == 0) bb[NB] = E;
}

// ---- phase C: scatter edges into coarse-bucket-grouped ebuf --------------
__global__ __launch_bounds__(256) void k_bscatter(
    const int* __restrict__ src, const int* __restrict__ dst,
    const int* __restrict__ blkhist, const int* __restrict__ bb,
    int* __restrict__ ebuf, int E, int chunk) {
  __shared__ int cur[NB];
  const int t = threadIdx.x, b = blockIdx.x;
  if (t < NB) cur[t] = bb[t] + blkhist[b * NB + t];
  __syncthreads();
  const int e0 = b * chunk;
  int e1 = e0 + chunk;
  if (e1 > E) e1 = E;
  for (int e = e0 + t; e < e1; e += 256) {
    int d = dst[e], s = src[e];
    int pos = atomicAdd(&cur[d >> 8], 1);
    ebuf[pos] = (s << 8) | (d & 255);
  }
}

// ---- fused L1 aggregate + epilogue + L2 projection -----------------------
// One block per 256-node bucket. 32 gather-groups of 32 lanes; lane j owns
// feature j. acc[n][j]: addr stride 32 floats -> lane j always hits bank j
// (conflict-free; 2 groups/wave on same bank set = free 2-way).
__global__ __launch_bounds__(1024) void k_fagg1(
    const float* __restrict__ zc, const int* __restrict__ ebuf,
    const int* __restrict__ bb, const float* __restrict__ b1,
    const float* __restrict__ W2l, const float* __restrict__ W2r,
    float* __restrict__ z2, int N) {
  __shared__ float acc[256 * 32];   // 32 KB
  __shared__ float w2p[32 * 64];    // 8 KB: [j][0:32]=W2l[j], [32:64]=W2r[j]
  __shared__ int cnt[256];
  __shared__ float bsh[32];
  const int t = threadIdx.x;
  const int k = blockIdx.x;
  for (int i = t; i < 256 * 32; i += 1024) acc[i] = 0.f;
  if (t < 256) cnt[t] = 0;
  for (int i = t; i < 2048; i += 1024) {
    int j = i >> 6, c = i & 63;
    w2p[i] = (c < 32) ? W2l[j * 32 + c] : W2r[j * 32 + (c - 32)];
  }
  if (t < 32) bsh[t] = b1[t];
  __syncthreads();

  const int r0 = bb[k], r1 = bb[k + 1];
  const int gid = t >> 5, j = t & 31;
  int e = r0 + gid;
  for (; e + 96 < r1; e += 128) {
    int v0 = ebuf[e], v1 = ebuf[e + 32], v2 = ebuf[e + 64], v3 = ebuf[e + 96];
    float f0 = zc[(size_t)(v0 >> 8) * 64 + j];
    float f1 = zc[(size_t)(v1 >> 8) * 64 + j];
    float f2 = zc[(size_t)(v2 >> 8) * 64 + j];
    float f3 = zc[(size_t)(v3 >> 8) * 64 + j];
    atomicAdd(&acc[(v0 & 255) * 32 + j], f0);
    atomicAdd(&acc[(v1 & 255) * 32 + j], f1);
    atomicAdd(&acc[(v2 & 255) * 32 + j], f2);
    atomicAdd(&acc[(v3 & 255) * 32 + j], f3);
    if (j == 0) {
      atomicAdd(&cnt[v0 & 255], 1);
      atomicAdd(&cnt[v1 & 255], 1);
      atomicAdd(&cnt[v2 & 255], 1);
      atomicAdd(&cnt[v3 & 255], 1);
    }
  }
  for (; e < r1; e += 32) {
    int v = ebuf[e];
    float f = zc[(size_t)(v >> 8) * 64 + j];
    atomicAdd(&acc[(v & 255) * 32 + j], f);
    if (j == 0) atomicAdd(&cnt[v & 255], 1);
  }
  __syncthreads();

  // epilogue: group gid owns nodes gid*8 .. gid*8+7
  const int n0 = k << 8;
#pragma unroll
  for (int i = 0; i < 8; i++) {
    const int nl = gid * 8 + i;
    const int node = n0 + nl;
    if (node >= N) break;  // uniform within the 32-lane group
    const int dg = cnt[nl];
    float h = acc[nl * 32 + j] / (float)(dg > 1 ? dg : 1) + bsh[j] +
              zc[(size_t)node * 64 + 32 + j];
    h = fmaxf(h, 0.f);
    float a0 = 0.f, a1 = 0.f;
#pragma unroll
    for (int jj = 0; jj < 32; jj++) {
      float hj = __shfl(h, jj, 32);
      a0 += hj * w2p[jj * 64 + j];
      a1 += hj * w2p[jj * 64 + 32 + j];
    }
    z2[(size_t)node * 64 + j] = a0;
    z2[(size_t)node * 64 + 32 + j] = a1;
  }
}

// ---- fused L2 aggregate + epilogue -> out --------------------------------
__global__ __launch_bounds__(1024) void k_fagg2(
    const float* __restrict__ z2, const int* __restrict__ ebuf,
    const int* __restrict__ bb, const float* __restrict__ b2,
    float* __restrict__ out, int N) {
  __shared__ float acc[256 * 32];
  __shared__ int cnt[256];
  __shared__ float bsh[32];
  const int t = threadIdx.x;
  const int k = blockIdx.x;
  for (int i = t; i < 256 * 32; i += 1024) acc[i] = 0.f;
  if (t < 256) cnt[t] = 0;
  if (t < 32) bsh[t] = b2[t];
  __syncthreads();

  const int r0 = bb[k], r1 = bb[k + 1];
  const int gid = t >> 5, j = t & 31;
  int e = r0 + gid;
  for (; e + 96 < r1; e += 128) {
    int v0 = ebuf[e], v1 = ebuf[e + 32], v2 = ebuf[e + 64], v3 = ebuf[e + 96];
    float f0 = z2[(size_t)(v0 >> 8) * 64 + j];
    float f1 = z2[(size_t)(v1 >> 8) * 64 + j];
    float f2 = z2[(size_t)(v2 >> 8) * 64 + j];
    float f3 = z2[(size_t)(v3 >> 8) * 64 + j];
    atomicAdd(&acc[(v0 & 255) * 32 + j], f0);
    atomicAdd(&acc[(v1 & 255) * 32 + j], f1);
    atomicAdd(&acc[(v2 & 255) * 32 + j], f2);
    atomicAdd(&acc[(v3 & 255) * 32 + j], f3);
    if (j == 0) {
      atomicAdd(&cnt[v0 & 255], 1);
      atomicAdd(&cnt[v1 & 255], 1);
      atomicAdd(&cnt[v2 & 255], 1);
      atomicAdd(&cnt[v3 & 255], 1);
    }
  }
  for (; e < r1; e += 32) {
    int v = ebuf[e];
    float f = z2[(size_t)(v >> 8) * 64 + j];
    atomicAdd(&acc[(v & 255) * 32 + j], f);
    if (j == 0) atomicAdd(&cnt[v & 255], 1);
  }
  __syncthreads();

  const int n0 = k << 8;
#pragma unroll
  for (int i = 0; i < 8; i++) {
    const int nl = gid * 8 + i;
    const int node = n0 + nl;
    if (node >= N) break;
    const int dg = cnt[nl];
    float v = acc[nl * 32 + j] / (float)(dg > 1 ? dg : 1) + bsh[j] +
              z2[(size_t)node * 64 + 32 + j];
    out[(size_t)node * 32 + j] = v;
  }
}

extern "C" void kernel_launch(void* const* d_in, const int* in_sizes, int n_in,
                              void* d_out, int out_size, void* d_ws,
                              size_t ws_size, hipStream_t stream) {
  const float* x = (const float*)d_in[0];
  const int* ei = (const int*)d_in[1];  // int32 (harness narrows int64)
  const float* W1l = (const float*)d_in[2];
  const float* b1 = (const float*)d_in[3];
  const float* W1r = (const float*)d_in[4];
  const float* W2l = (const float*)d_in[5];
  const float* b2 = (const float*)d_in[6];
  const float* W2r = (const float*)d_in[7];
  float* out = (float*)d_out;

  const int N = N_NODES;
  const int E = in_sizes[1] / 2;  // 800000

  float* zc = (float*)d_ws;                    // N*64 floats
  float* zc2 = zc + (size_t)N * 64;            // N*64 floats
  int* ebuf = (int*)(zc2 + (size_t)N * 64);    // E
  int* bb = ebuf + E;                          // NB+1
  int* blkhist = bb + NB + 1;                  // GB*NB

  const int* srcp = ei;
  const int* dstp = ei + E;

  const int chunk = (E + GB - 1) / GB;
  const int nblk_proj = (N + 63) / 64;  // 782

  k_bcount<<<GB, 256, 0, stream>>>(dstp, blkhist, E, chunk);
  k_bscan<<<1, 256, 0, stream>>>(blkhist, bb, E);
  k_bscatter<<<GB, 256, 0, stream>>>(srcp, dstp, blkhist, bb, ebuf, E, chunk);
  kproj<<<nblk_proj, 256, 0, stream>>>(x, W1l, W1r, zc, N, 128);
  k_fagg1<<<NB, 1024, 0, stream>>>(zc, ebuf, bb, b1, W2l, W2r, zc2, N);
  k_fagg2<<<NB, 1024, 0, stream>>>(zc2, ebuf, bb, b2, out, N);
}